// Round 1
// 774.565 us; speedup vs baseline: 1.0414x; 1.0414x over previous
//
#include <hip/hip_runtime.h>
#include <stdint.h>

// ---------- types / helpers ----------
typedef __bf16 bf16x8 __attribute__((ext_vector_type(8)));
typedef float  f32x4  __attribute__((ext_vector_type(4)));

#define DEV __device__ __forceinline__

DEV unsigned short f2bf(float f) {
    unsigned int u = __float_as_uint(f);
    unsigned int r = (u + 0x7fffu + ((u >> 16) & 1u)) >> 16;   // RNE
    return (unsigned short)r;
}
DEV float bf2f(unsigned short s) {
    return __uint_as_float(((unsigned int)s) << 16);
}

typedef __attribute__((address_space(1))) const void gv_t;
typedef __attribute__((address_space(3))) void lv_t;
DEV void stage16(const unsigned short* g, unsigned short* l) {
    // async global->LDS DMA, 16B/lane, LDS dest = wave-uniform base + lane*16
    __builtin_amdgcn_global_load_lds((gv_t*)g, (lv_t*)l, 16, 0, 0);
}

// ---------- vectorized fp32 -> bf16 (8 elements / thread) ----------
__global__ __launch_bounds__(256) void cvt8_kernel(const float* __restrict__ src,
                                                   unsigned short* __restrict__ dst, int n8) {
    int i = blockIdx.x * blockDim.x + threadIdx.x;
    if (i >= n8) return;
    const float4* s = (const float4*)(src + (size_t)i * 8);
    float4 x = s[0], y = s[1];
    uint4 pk; unsigned short* p = (unsigned short*)&pk;
    p[0]=f2bf(x.x); p[1]=f2bf(x.y); p[2]=f2bf(x.z); p[3]=f2bf(x.w);
    p[4]=f2bf(y.x); p[5]=f2bf(y.y); p[6]=f2bf(y.z); p[7]=f2bf(y.w);
    ((uint4*)dst)[i] = pk;
}

// ---------- q = joint_queries @ wq^T + bq  (coalesced wave-dot version) ----------
__global__ __launch_bounds__(256) void qproj2_kernel(const float* __restrict__ jq,
                                                     const float* __restrict__ ipw,
                                                     const float* __restrict__ ipb,
                                                     float* __restrict__ q) {
    __shared__ float zq[512];
    const int j = blockIdx.x, cq = blockIdx.y, t = threadIdx.x;
    zq[t] = jq[j * 512 + t];
    zq[t + 256] = jq[j * 512 + t + 256];
    __syncthreads();
    const int wv = t >> 6, lane = t & 63;
    for (int i = 0; i < 32; ++i) {
        int c = cq * 128 + wv * 32 + i;
        const float* wr = ipw + (size_t)c * 512 + lane * 8;
        float4 a = *(const float4*)wr;
        float4 bq = *(const float4*)(wr + 4);
        const float* zp = zq + lane * 8;
        float p = a.x*zp[0] + a.y*zp[1] + a.z*zp[2] + a.w*zp[3]
                + bq.x*zp[4] + bq.y*zp[5] + bq.z*zp[6] + bq.w*zp[7];
        for (int m = 32; m; m >>= 1) p += __shfl_xor(p, m);
        if (lane == 0) q[j * 512 + c] = p + ipb[c];
    }
}

// ---------- qk_fold[hj][e] = (1/8) sum_d q[j][h*64+d]*wk[h*64+d][e] -> Bcat rows 0..191 ----------
__global__ __launch_bounds__(256) void qkfold_kernel(const float* __restrict__ q,
                                                     const float* __restrict__ ipw,
                                                     const float* __restrict__ ipb,
                                                     unsigned short* __restrict__ Bcat,
                                                     float* __restrict__ bias1) {
    int hj = blockIdx.x;                // hj = h*24 + j
    int h = hj / 24, j = hj - h * 24;
    int t = threadIdx.x;
    __shared__ float qh[64];
    if (t < 64) qh[t] = q[j * 512 + h * 64 + t];
    __syncthreads();
    for (int e = t; e < 512; e += 256) {
        float acc = 0.f;
        for (int d = 0; d < 64; ++d)
            acc += qh[d] * ipw[(size_t)(512 + h * 64 + d) * 512 + e];
        Bcat[(size_t)hj * 512 + e] = f2bf(acc * 0.125f);
    }
    if (t == 0) {
        float acc = 0.f;
        for (int d = 0; d < 64; ++d) acc += qh[d] * ipb[512 + h * 64 + d];
        bias1[hj] = acc * 0.125f;
    }
}

// ---------- pad: Bcat rows 704..767 = 0, bias1[192..767] ----------
__global__ __launch_bounds__(256) void pad_kernel(unsigned short* __restrict__ Bcat,
                                                  float* __restrict__ bias1,
                                                  const float* __restrict__ ipb) {
    int idx = blockIdx.x * 256 + threadIdx.x;
    if (idx < 32768) Bcat[(size_t)704 * 512 + idx] = 0;
    if (idx < 512) bias1[192 + idx] = ipb[1024 + idx];
    if (idx < 64) bias1[704 + idx] = 0.f;
}

// ---------- opT[j][k] = bf16(opw[k][j]) ----------
__global__ __launch_bounds__(256) void transp_kernel(const float* __restrict__ opw,
                                                     unsigned short* __restrict__ opT) {
    int j = blockIdx.x;
    for (int k = threadIdx.x; k < 512; k += 256)
        opT[(size_t)j * 512 + k] = f2bf(opw[(size_t)k * 512 + j]);
}

// ---------- bfold[i] = w1[i,:].opb + b1[i]  (fp32) ----------
__global__ __launch_bounds__(256) void bfold_kernel(const float* __restrict__ w1,
                                                    const float* __restrict__ opb,
                                                    const float* __restrict__ b1,
                                                    float* __restrict__ bfold) {
    __shared__ float ob[512];
    int t = threadIdx.x;
    ob[t] = opb[t]; ob[t + 256] = opb[t + 256];
    __syncthreads();
    int i = blockIdx.x * 256 + t;
    float acc = b1[i];
    const float* wr = w1 + (size_t)i * 512;
    for (int k = 0; k < 512; ++k) acc += wr[k] * ob[k];
    bfold[i] = acc;
}

// ---------- gemm128: C(M,N)=A@B^T + bias, 128x128 tile, row-major C (for Wfold) ----------
__global__ __launch_bounds__(256) void gemm128(const unsigned short* __restrict__ A,
                                               const unsigned short* __restrict__ B,
                                               const float* __restrict__ bias,
                                               unsigned short* __restrict__ C,
                                               int K, int ldc) {
    __shared__ unsigned short As[4096];
    __shared__ unsigned short Bs[4096];
    const int tid = threadIdx.x, wv = tid >> 6, lane = tid & 63;
    const int m0 = blockIdx.y << 7, n0 = blockIdx.x << 7;
    const int wr = wv >> 1, wc = wv & 1;
    const int srow = lane >> 2, scol = (lane & 3) << 3;
    const int c0 = wv << 1;
    const unsigned short* pA = A + (size_t)(m0 + c0 * 16 + srow) * K + scol;
    const unsigned short* pB = B + (size_t)(n0 + c0 * 16 + srow) * K + scol;
    unsigned short* lA = As + (c0 << 9);
    unsigned short* lB = Bs + (c0 << 9);
    const size_t rowStep = (size_t)16 * K;

    f32x4 acc[4][4];
#pragma unroll
    for (int i = 0; i < 4; ++i)
#pragma unroll
        for (int j = 0; j < 4; ++j) acc[i][j] = f32x4{0.f, 0.f, 0.f, 0.f};

    const int row16 = lane & 15, kg8 = (lane >> 4) << 3;
    const int aoff = ((wr << 6) + row16) * 32 + kg8;
    const int boff = ((wc << 6) + row16) * 32 + kg8;

    for (int kb = 0; kb < K; kb += 32) {
        stage16(pA + kb, lA);
        stage16(pA + rowStep + kb, lA + 512);
        stage16(pB + kb, lB);
        stage16(pB + rowStep + kb, lB + 512);
        __syncthreads();
        bf16x8 a[4], b[4];
#pragma unroll
        for (int i = 0; i < 4; ++i) a[i] = *(const bf16x8*)&As[aoff + (i << 9)];
#pragma unroll
        for (int j = 0; j < 4; ++j) b[j] = *(const bf16x8*)&Bs[boff + (j << 9)];
#pragma unroll
        for (int i = 0; i < 4; ++i)
#pragma unroll
            for (int j = 0; j < 4; ++j)
                acc[i][j] = __builtin_amdgcn_mfma_f32_16x16x32_bf16(a[i], b[j], acc[i][j], 0, 0, 0);
        __syncthreads();
    }
    const int cg = lane >> 4, col = lane & 15;
#pragma unroll
    for (int j = 0; j < 4; ++j) {
        int gn = n0 + (wc << 6) + (j << 4) + col;
        float bv = bias ? bias[gn] : 0.f;
#pragma unroll
        for (int i = 0; i < 4; ++i) {
            int gmb = m0 + (wr << 6) + (i << 4) + (cg << 2);
#pragma unroll
            for (int rr = 0; rr < 4; ++rr)
                C[(size_t)(gmb + rr) * ldc + gn] = f2bf(acc[i][j][rr] + bv);
        }
    }
}

// ================================================================================
// gemm256T: fused scores|V GEMM, 256x256 tile, BK=32, 8-wave, 4-deep LDS ring,
// counted-vmcnt pipeline (T3+T4), XOR bank swizzle (T2), setprio (T5), XCD swizzle (T1).
// Transposed store: CT[n][m], ldcT = M = 131072, rows >= 704 skipped.
//
// Schedule (per K-tile c, 2 phases):
//   phase qm=0: ds_read A-frags(qm=0)+B-frags of tile c; stage A0,A1 of tile c+3;
//               barrier; lgkmcnt(0); setprio(1); 16 MFMA; setprio(0); barrier
//   phase qm=1: ds_read A-frags(qm=1)+B-frags of tile c; stage B0,B1 of tile c+3;
//               s_waitcnt vmcnt(8)  <-- gate for tile c+1, BEFORE closing barrier
//               barrier; ... 16 MFMA ...; barrier
// Gate ledger (1 load/half/wave, halves of tile t issue at positions 4t+1..4t+4):
//   at gate for tile t, newer-than-B1[t] loads = tiles t+1,t+2 = 8  -> vmcnt(8)
//   tail: gate tile 14 -> vmcnt(4), gate tile 15 -> vmcnt(0). Never vmcnt(0) mid-loop.
// Swizzle: 16B-chunk' = chunk ^ ((row>>1)&3), applied to BOTH the global source of
// global_load_lds (linear LDS dest) and the ds_read address (rule 21).
// ================================================================================
#define GEM_NOGATE
#define GEM_GATE8 asm volatile("s_waitcnt vmcnt(8)" ::: "memory");
#define GEM_GATE4 asm volatile("s_waitcnt vmcnt(4)" ::: "memory");
#define GEM_GATE0 asm volatile("s_waitcnt vmcnt(0)" ::: "memory");

#define G_PHASE(c_, qm_, SA_, SB_, GATE_)                                              \
  {                                                                                    \
    const unsigned short* Ab_ = &lds[(c_) & 3][0][wr][0];                              \
    const unsigned short* Bb_ = &lds[(c_) & 3][1][bhalf][bqoff];                       \
    bf16x8 a0_ = *(const bf16x8*)&Ab_[rdo + ((qm_)*4 + 0) * 512];                      \
    bf16x8 a1_ = *(const bf16x8*)&Ab_[rdo + ((qm_)*4 + 1) * 512];                      \
    bf16x8 a2_ = *(const bf16x8*)&Ab_[rdo + ((qm_)*4 + 2) * 512];                      \
    bf16x8 a3_ = *(const bf16x8*)&Ab_[rdo + ((qm_)*4 + 3) * 512];                      \
    bf16x8 b0_ = *(const bf16x8*)&Bb_[rdo + 0 * 512];                                  \
    bf16x8 b1_ = *(const bf16x8*)&Bb_[rdo + 1 * 512];                                  \
    bf16x8 b2_ = *(const bf16x8*)&Bb_[rdo + 2 * 512];                                  \
    bf16x8 b3_ = *(const bf16x8*)&Bb_[rdo + 3 * 512];                                  \
    if (SA_) { const int tt_ = (c_) + 3;                                               \
      stage16(pA0 + tt_ * 32, &lds[tt_ & 3][0][0][w << 9]);                            \
      stage16(pA1 + tt_ * 32, &lds[tt_ & 3][0][1][w << 9]); }                          \
    if (SB_) { const int tt_ = (c_) + 3;                                               \
      stage16(pB0 + tt_ * 32, &lds[tt_ & 3][1][0][w << 9]);                            \
      stage16(pB1 + tt_ * 32, &lds[tt_ & 3][1][1][w << 9]); }                          \
    GATE_                                                                              \
    __builtin_amdgcn_s_barrier();                                                      \
    asm volatile("s_waitcnt lgkmcnt(0)" ::: "memory");                                 \
    __builtin_amdgcn_sched_barrier(0);                                                 \
    __builtin_amdgcn_s_setprio(1);                                                     \
    acc[(qm_)*4+0][0] = __builtin_amdgcn_mfma_f32_16x16x32_bf16(a0_, b0_, acc[(qm_)*4+0][0], 0, 0, 0); \
    acc[(qm_)*4+0][1] = __builtin_amdgcn_mfma_f32_16x16x32_bf16(a0_, b1_, acc[(qm_)*4+0][1], 0, 0, 0); \
    acc[(qm_)*4+0][2] = __builtin_amdgcn_mfma_f32_16x16x32_bf16(a0_, b2_, acc[(qm_)*4+0][2], 0, 0, 0); \
    acc[(qm_)*4+0][3] = __builtin_amdgcn_mfma_f32_16x16x32_bf16(a0_, b3_, acc[(qm_)*4+0][3], 0, 0, 0); \
    acc[(qm_)*4+1][0] = __builtin_amdgcn_mfma_f32_16x16x32_bf16(a1_, b0_, acc[(qm_)*4+1][0], 0, 0, 0); \
    acc[(qm_)*4+1][1] = __builtin_amdgcn_mfma_f32_16x16x32_bf16(a1_, b1_, acc[(qm_)*4+1][1], 0, 0, 0); \
    acc[(qm_)*4+1][2] = __builtin_amdgcn_mfma_f32_16x16x32_bf16(a1_, b2_, acc[(qm_)*4+1][2], 0, 0, 0); \
    acc[(qm_)*4+1][3] = __builtin_amdgcn_mfma_f32_16x16x32_bf16(a1_, b3_, acc[(qm_)*4+1][3], 0, 0, 0); \
    acc[(qm_)*4+2][0] = __builtin_amdgcn_mfma_f32_16x16x32_bf16(a2_, b0_, acc[(qm_)*4+2][0], 0, 0, 0); \
    acc[(qm_)*4+2][1] = __builtin_amdgcn_mfma_f32_16x16x32_bf16(a2_, b1_, acc[(qm_)*4+2][1], 0, 0, 0); \
    acc[(qm_)*4+2][2] = __builtin_amdgcn_mfma_f32_16x16x32_bf16(a2_, b2_, acc[(qm_)*4+2][2], 0, 0, 0); \
    acc[(qm_)*4+2][3] = __builtin_amdgcn_mfma_f32_16x16x32_bf16(a2_, b3_, acc[(qm_)*4+2][3], 0, 0, 0); \
    acc[(qm_)*4+3][0] = __builtin_amdgcn_mfma_f32_16x16x32_bf16(a3_, b0_, acc[(qm_)*4+3][0], 0, 0, 0); \
    acc[(qm_)*4+3][1] = __builtin_amdgcn_mfma_f32_16x16x32_bf16(a3_, b1_, acc[(qm_)*4+3][1], 0, 0, 0); \
    acc[(qm_)*4+3][2] = __builtin_amdgcn_mfma_f32_16x16x32_bf16(a3_, b2_, acc[(qm_)*4+3][2], 0, 0, 0); \
    acc[(qm_)*4+3][3] = __builtin_amdgcn_mfma_f32_16x16x32_bf16(a3_, b3_, acc[(qm_)*4+3][3], 0, 0, 0); \
    __builtin_amdgcn_s_setprio(0);                                                     \
    __builtin_amdgcn_s_barrier();                                                      \
  }

__global__ __launch_bounds__(512) void gemm256T(const unsigned short* __restrict__ A,
                                                const unsigned short* __restrict__ B,
                                                const float* __restrict__ bias,
                                                unsigned short* __restrict__ CT) {
    constexpr int K = 512;
    constexpr int LDCT = 131072;
    constexpr int NSTORE = 704;
    // [buf 0..3][A=0/B=1][half 0..1][128 rows x 32 cols] = 128 KB
    __shared__ unsigned short lds[4][2][2][4096];

    const int tid = threadIdx.x;
    const int w = tid >> 6, l = tid & 63;
    const int wr = w >> 2, wc = w & 3;               // 2x4 wave grid -> 128x64 per wave
    const int row16 = l & 15, kchunk = l >> 4;       // fragment coords
    const int cg = l >> 4, col = l & 15;             // C/D layout coords

    // bijective XCD swizzle: 1536 wgs = 8 XCDs x 192; each XCD gets contiguous m-range
    const int bid = blockIdx.x;
    const int wg = (bid & 7) * 192 + (bid >> 3);
    const int mt = wg / 3, nt = wg - mt * 3;
    const int m0 = mt << 8, n0 = nt << 8;

    // staging source (per-thread), pre-swizzled chunk:  chunk' = chunk ^ ((row>>1)&3)
    const int st_r = (w << 4) + (l >> 2);            // row within 128-row half
    const int st_c = (l & 3) ^ ((l >> 3) & 3);       // logical 16B chunk for this lane
    const unsigned short* pA0 = A + (size_t)(m0 + st_r) * K + (st_c << 3);
    const unsigned short* pA1 = A + (size_t)(m0 + 128 + st_r) * K + (st_c << 3);
    const unsigned short* pB0 = B + (size_t)(n0 + st_r) * K + (st_c << 3);
    const unsigned short* pB1 = B + (size_t)(n0 + 128 + st_r) * K + (st_c << 3);

    // ds_read offset in shorts: row16*32 + swizzled_chunk*8 (same XOR as staging)
    const int rdo = row16 * 32 + ((kchunk ^ ((row16 >> 1) & 3)) << 3);
    const int bhalf = wc >> 1, bqoff = (wc & 1) << 11;   // B half + 64-row sub-offset

    f32x4 acc[8][4];
#pragma unroll
    for (int i = 0; i < 8; ++i)
#pragma unroll
        for (int j = 0; j < 4; ++j) acc[i][j] = f32x4{0.f, 0.f, 0.f, 0.f};

    // prologue: stage tiles 0,1,2 (12 loads/wave); drain to 8 -> tile 0 landed
#pragma unroll
    for (int t = 0; t < 3; ++t) {
        stage16(pA0 + t * 32, &lds[t][0][0][w << 9]);
        stage16(pA1 + t * 32, &lds[t][0][1][w << 9]);
        stage16(pB0 + t * 32, &lds[t][1][0][w << 9]);
        stage16(pB1 + t * 32, &lds[t][1][1][w << 9]);
    }
    asm volatile("s_waitcnt vmcnt(8)" ::: "memory");
    __builtin_amdgcn_s_barrier();

    // main loop: tiles 0..12 stage tile c+3 and gate tile c+1 at vmcnt(8)
    for (int c = 0; c < 13; ++c) {
        G_PHASE(c, 0, 1, 0, GEM_NOGATE)
        G_PHASE(c, 1, 0, 1, GEM_GATE8)
    }
    // tail: no more staging; gates drain 8 -> 4 -> 0
    G_PHASE(13, 0, 0, 0, GEM_NOGATE)
    G_PHASE(13, 1, 0, 0, GEM_GATE4)
    G_PHASE(14, 0, 0, 0, GEM_NOGATE)
    G_PHASE(14, 1, 0, 0, GEM_GATE0)
    G_PHASE(15, 0, 0, 0, GEM_NOGATE)
    G_PHASE(15, 1, 0, 0, GEM_NOGATE)

    // epilogue: transposed bf16 store, 8B packed per 4 rows
#pragma unroll
    for (int nf = 0; nf < 4; ++nf) {
        int gn = n0 + (wc << 6) + (nf << 4) + col;
        if (gn < NSTORE) {
            float bv = bias[gn];
            unsigned short* rowp = CT + (size_t)gn * LDCT;
#pragma unroll
            for (int mf = 0; mf < 8; ++mf) {
                int gmb = m0 + (wr << 7) + (mf << 4) + (cg << 2);
                ushort4 pk;
                pk.x = f2bf(acc[mf][nf][0] + bv);
                pk.y = f2bf(acc[mf][nf][1] + bv);
                pk.z = f2bf(acc[mf][nf][2] + bv);
                pk.w = f2bf(acc[mf][nf][3] + bv);
                *(ushort4*)(rowp + gmb) = pk;
            }
        }
    }
}

// ---------- mega: per-b attention (softmax+PV) + Wfold GEMM + LN/SiLU/w2 + chain ----------
__global__ __launch_bounds__(256) void mega_kernel(const unsigned short* __restrict__ scTV,
                                                   const unsigned short* __restrict__ Wfold,
                                                   const float* __restrict__ bfold,
                                                   const float* __restrict__ ln_g,
                                                   const float* __restrict__ ln_b,
                                                   const float* __restrict__ w2,
                                                   const float* __restrict__ b2,
                                                   const int* __restrict__ parent,
                                                   float* __restrict__ out) {
    const int b = blockIdx.x, tid = threadIdx.x;
    const int wv = tid >> 6, lane = tid & 63;
    const int row16 = lane & 15, kg8 = (lane >> 4) << 3;
    const int cg = lane >> 4, col = lane & 15;

    __shared__ unsigned short pmat[32 * 128];    // P (one head), rows 24..31 garbage (unused)
    __shared__ unsigned short vtB[16384];        // phase A: vt[64][128]; phase B: Bst[4][128*32]
    __shared__ unsigned short otile[32 * 520];   // o-tile, stride 520 (16B-aligned, 2-way banks)
    __shared__ float red1[32][4], red2[32][4];
    __shared__ float mus[32], rstds[32];
    __shared__ float dred[24][4][4];
    __shared__ float offs[24][3];

    const size_t colbase = (size_t)b * 128 + (size_t)(lane & 15) * 8;

    // ================= Phase A: attention =================
    for (int h = 0; h < 8; ++h) {
        if (wv < 3) {   // stage P rows: waves 0..2, 8 rows each (2 DMA instrs)
            const size_t r0 = (size_t)(h * 24 + 8 * wv + (lane >> 4));
            stage16(scTV + r0 * 131072 + colbase, pmat + (8 * wv) * 128);
            stage16(scTV + (r0 + 4) * 131072 + colbase, pmat + (8 * wv + 4) * 128);
        }
#pragma unroll
        for (int g = 0; g < 4; ++g) {   // stage V^T rows: each wave 16 rows
            const size_t r0 = (size_t)(192 + h * 64 + 16 * wv + 4 * g + (lane >> 4));
            stage16(scTV + r0 * 131072 + colbase, vtB + (16 * wv + 4 * g) * 128);
        }
        __syncthreads();

        // softmax over s (128) for rows wv*6 .. +6
        for (int i = 0; i < 6; ++i) {
            int j = wv * 6 + i;
            float x0 = bf2f(pmat[j * 128 + lane]);
            float x1 = bf2f(pmat[j * 128 + 64 + lane]);
            float mx = fmaxf(x0, x1);
            for (int m = 32; m; m >>= 1) mx = fmaxf(mx, __shfl_xor(mx, m));
            float e0 = __expf(x0 - mx), e1 = __expf(x1 - mx);
            float sm = e0 + e1;
            for (int m = 32; m; m >>= 1) sm += __shfl_xor(sm, m);
            float inv = 1.f / sm;
            pmat[j * 128 + lane] = f2bf(e0 * inv);
            pmat[j * 128 + 64 + lane] = f2bf(e1 * inv);
        }
        __syncthreads();

        // PV: wave handles d-cols [wv*16, wv*16+16)
        f32x4 pv0 = {0.f,0.f,0.f,0.f}, pv1 = {0.f,0.f,0.f,0.f};
#pragma unroll
        for (int ks = 0; ks < 4; ++ks) {
            bf16x8 a0 = *(const bf16x8*)&pmat[row16 * 128 + ks * 32 + kg8];
            bf16x8 a1 = *(const bf16x8*)&pmat[(16 + row16) * 128 + ks * 32 + kg8];
            bf16x8 bf = *(const bf16x8*)&vtB[(wv * 16 + row16) * 128 + ks * 32 + kg8];
            pv0 = __builtin_amdgcn_mfma_f32_16x16x32_bf16(a0, bf, pv0, 0, 0, 0);
            pv1 = __builtin_amdgcn_mfma_f32_16x16x32_bf16(a1, bf, pv1, 0, 0, 0);
        }
#pragma unroll
        for (int rr = 0; rr < 4; ++rr) {
            int j0 = cg * 4 + rr;
            otile[j0 * 520 + h * 64 + wv * 16 + col] = f2bf(pv0[rr]);
            int j1 = 16 + cg * 4 + rr;
            if (j1 < 24)
                otile[j1 * 520 + h * 64 + wv * 16 + col] = f2bf(pv1[rr]);
        }
        __syncthreads();
    }

    // ================= Phase B: h = otile @ Wfold^T + bfold =================
    const int ns = wv << 7;                      // wave's 128-col slice
    unsigned short* Bst = vtB + (wv << 12);      // 8 KB per wave

    f32x4 acc[2][8];
#pragma unroll
    for (int mt = 0; mt < 2; ++mt)
#pragma unroll
        for (int nt = 0; nt < 8; ++nt) acc[mt][nt] = f32x4{0.f,0.f,0.f,0.f};

    for (int kb = 0; kb < 512; kb += 32) {
#pragma unroll
        for (int g = 0; g < 8; ++g)
            stage16(Wfold + (size_t)(ns + 16 * g + (lane >> 2)) * 512 + kb + (lane & 3) * 8,
                    Bst + 16 * g * 32);
        __syncthreads();
        bf16x8 a0 = *(const bf16x8*)&otile[row16 * 520 + kb + kg8];
        bf16x8 a1 = *(const bf16x8*)&otile[(16 + row16) * 520 + kb + kg8];
#pragma unroll
        for (int nt = 0; nt < 8; ++nt) {
            bf16x8 bf = *(const bf16x8*)&Bst[(nt * 16 + row16) * 32 + kg8];
            acc[0][nt] = __builtin_amdgcn_mfma_f32_16x16x32_bf16(a0, bf, acc[0][nt], 0, 0, 0);
            acc[1][nt] = __builtin_amdgcn_mfma_f32_16x16x32_bf16(a1, bf, acc[1][nt], 0, 0, 0);
        }
        __syncthreads();
    }

    // bias + LN stats (per-row partial sums, 16-lane groups then cross-wave via LDS)
    int gcol[8]; float bvv[8];
#pragma unroll
    for (int nt = 0; nt < 8; ++nt) { gcol[nt] = ns + nt * 16 + col; bvv[nt] = bfold[gcol[nt]]; }
#pragma unroll
    for (int mt = 0; mt < 2; ++mt)
#pragma unroll
        for (int nt = 0; nt < 8; ++nt)
#pragma unroll
            for (int rr = 0; rr < 4; ++rr) acc[mt][nt][rr] += bvv[nt];

#pragma unroll
    for (int mt = 0; mt < 2; ++mt)
#pragma unroll
        for (int rr = 0; rr < 4; ++rr) {
            float s1 = 0.f, s2 = 0.f;
#pragma unroll
            for (int nt = 0; nt < 8; ++nt) { float v = acc[mt][nt][rr]; s1 += v; s2 += v * v; }
            s1 += __shfl_xor(s1, 1); s2 += __shfl_xor(s2, 1);
            s1 += __shfl_xor(s1, 2); s2 += __shfl_xor(s2, 2);
            s1 += __shfl_xor(s1, 4); s2 += __shfl_xor(s2, 4);
            s1 += __shfl_xor(s1, 8); s2 += __shfl_xor(s2, 8);
            if (col == 0) { int r = mt * 16 + cg * 4 + rr; red1[r][wv] = s1; red2[r][wv] = s2; }
        }
    __syncthreads();
    if (tid < 32) {
        float s1 = red1[tid][0] + red1[tid][1] + red1[tid][2] + red1[tid][3];
        float s2 = red2[tid][0] + red2[tid][1] + red2[tid][2] + red2[tid][3];
        float mu = s1 * (1.f / 512.f);
        float var = s2 * (1.f / 512.f) - mu * mu;
        mus[tid] = mu; rstds[tid] = rsqrtf(var + 1e-5f);
    }
    __syncthreads();

    // LN + SiLU + w2 partial dots
    float gg[8], bb[8], w2v[4][8];
#pragma unroll
    for (int nt = 0; nt < 8; ++nt) { gg[nt] = ln_g[gcol[nt]]; bb[nt] = ln_b[gcol[nt]]; }
#pragma unroll
    for (int c = 0; c < 4; ++c)
#pragma unroll
        for (int nt = 0; nt < 8; ++nt) w2v[c][nt] = w2[c * 512 + gcol[nt]];

#pragma unroll
    for (int mt = 0; mt < 2; ++mt)
#pragma unroll
        for (int rr = 0; rr < 4; ++rr) {
            int r = mt * 16 + cg * 4 + rr;
            float mu = mus[r], rs = rstds[r];
            float d0 = 0.f, d1 = 0.f, d2 = 0.f, d3 = 0.f;
#pragma unroll
            for (int nt = 0; nt < 8; ++nt) {
                float y = (acc[mt][nt][rr] - mu) * rs * gg[nt] + bb[nt];
                float sv = y / (1.f + __expf(-y));
                d0 += sv * w2v[0][nt]; d1 += sv * w2v[1][nt];
                d2 += sv * w2v[2][nt]; d3 += sv * w2v[3][nt];
            }
            d0 += __shfl_xor(d0, 1); d1 += __shfl_xor(d1, 1); d2 += __shfl_xor(d2, 1); d3 += __shfl_xor(d3, 1);
            d0 += __shfl_xor(d0, 2); d1 += __shfl_xor(d1, 2); d2 += __shfl_xor(d2, 2); d3 += __shfl_xor(d3, 2);
            d0 += __shfl_xor(d0, 4); d1 += __shfl_xor(d1, 4); d2 += __shfl_xor(d2, 4); d3 += __shfl_xor(d3, 4);
            d0 += __shfl_xor(d0, 8); d1 += __shfl_xor(d1, 8); d2 += __shfl_xor(d2, 8); d3 += __shfl_xor(d3, 8);
            if (col == 0 && r < 24) {
                dred[r][wv][0] = d0; dred[r][wv][1] = d1;
                dred[r][wv][2] = d2; dred[r][wv][3] = d3;
            }
        }
    __syncthreads();

    float* out_joints = out;
    float* out_off    = out + 73728;
    float* out_len    = out + 147456;
    if (tid < 24) {
        int j = tid;
        float rv[4];
#pragma unroll
        for (int c = 0; c < 4; ++c)
            rv[c] = dred[j][0][c] + dred[j][1][c] + dred[j][2][c] + dred[j][3][c] + b2[c];
        size_t ob = ((size_t)b * 24 + j) * 3;
        if (j == 0) {
            offs[0][0] = offs[0][1] = offs[0][2] = 0.f;
            out_off[ob] = 0.f; out_off[ob + 1] = 0.f; out_off[ob + 2] = 0.f;
        } else {
            float nrm = sqrtf(rv[0]*rv[0] + rv[1]*rv[1] + rv[2]*rv[2]);
            float inv = 1.f / fmaxf(nrm, 1e-6f);
            float lr = rv[3];
            float L = (lr > 0.f) ? lr + log1pf(expf(-lr)) : log1pf(expf(lr));
            float o0 = rv[0]*inv*L, o1 = rv[1]*inv*L, o2 = rv[2]*inv*L;
            offs[j][0] = o0; offs[j][1] = o1; offs[j][2] = o2;
            out_off[ob] = o0; out_off[ob + 1] = o1; out_off[ob + 2] = o2;
            out_len[(size_t)b * 23 + j - 1] = L;
        }
    }
    __syncthreads();
    if (tid < 3) {
        int d = tid;
        float cum[24]; cum[0] = 0.f;
        out_joints[(size_t)b * 24 * 3 + d] = 0.f;
        for (int j = 1; j < 24; ++j) {
            cum[j] = offs[j][d] + cum[parent[j]];
            out_joints[((size_t)b * 24 + j) * 3 + d] = cum[j];
        }
    }
}

// ---------- launch ----------
extern "C" void kernel_launch(void* const* d_in, const int* in_sizes, int n_in,
                              void* d_out, int out_size, void* d_ws, size_t ws_size,
                              hipStream_t stream) {
    const float* z    = (const float*)d_in[0];   // (1024,128,512)
    const float* jq   = (const float*)d_in[1];   // (1,24,512)
    const float* ipw  = (const float*)d_in[2];   // (1536,512)
    const float* ipb  = (const float*)d_in[3];   // (1536,)
    const float* opw  = (const float*)d_in[4];   // (512,512)
    const float* opb  = (const float*)d_in[5];
    const float* w1   = (const float*)d_in[6];   // (512,512)
    const float* b1   = (const float*)d_in[7];
    const float* lng  = (const float*)d_in[8];
    const float* lnb  = (const float*)d_in[9];
    const float* w2   = (const float*)d_in[10];  // (4,512)
    const float* b2   = (const float*)d_in[11];
    const int* parent = (const int*)d_in[12];
    float* out = (float*)d_out;

    char* ws = (char*)d_ws;
    size_t off = 0;
    auto alloc = [&](size_t bytes) {
        off = (off + 255) & ~(size_t)255;
        char* p = ws + off;
        off += bytes;
        return p;
    };

    unsigned short* zb    = (unsigned short*)alloc((size_t)67108864 * 2);        // 134 MB
    unsigned short* scTV  = (unsigned short*)alloc((size_t)704 * 131072 * 2);    // 184.5 MB
    unsigned short* Bcat  = (unsigned short*)alloc((size_t)768 * 512 * 2);
    float*          bias1 = (float*)alloc(768 * 4);
    float*          qf    = (float*)alloc((size_t)24 * 512 * 4);
    unsigned short* opT   = (unsigned short*)alloc((size_t)512 * 512 * 2);
    unsigned short* w1b   = (unsigned short*)alloc((size_t)512 * 512 * 2);
    unsigned short* Wfold = (unsigned short*)alloc((size_t)512 * 512 * 2);
    float*          bfold = (float*)alloc(512 * 4);

    // --- prep ---
    cvt8_kernel<<<32768, 256, 0, stream>>>(z, zb, 8388608);                       // z -> bf16
    cvt8_kernel<<<128, 256, 0, stream>>>(ipw + (size_t)1024 * 512,
                                         Bcat + (size_t)192 * 512, 32768);        // wv rows 192..703
    cvt8_kernel<<<128, 256, 0, stream>>>(w1, w1b, 32768);
    qproj2_kernel<<<dim3(24, 4), 256, 0, stream>>>(jq, ipw, ipb, qf);
    qkfold_kernel<<<192, 256, 0, stream>>>(qf, ipw, ipb, Bcat, bias1);            // rows 0..191
    pad_kernel<<<128, 256, 0, stream>>>(Bcat, bias1, ipb);
    transp_kernel<<<512, 256, 0, stream>>>(opw, opT);
    bfold_kernel<<<2, 256, 0, stream>>>(w1, opb, b1, bfold);
    gemm128<<<dim3(4, 4), 256, 0, stream>>>(w1b, opT, nullptr, Wfold, 512, 512);  // Wfold = w1@opw

    // --- fused scores|V GEMM, 256^2 tile, counted-vmcnt pipeline, transposed store ---
    gemm256T<<<1536, 512, 0, stream>>>(zb, Bcat, bias1, scTV);

    // --- per-b mega: attention + Wfold GEMM + LN/SiLU/w2 + chain ---
    mega_kernel<<<1024, 256, 0, stream>>>(scTV, Wfold, bfold, lng, lnb, w2, b2, parent, out);
}

// Round 2
// 773.992 us; speedup vs baseline: 1.0421x; 1.0007x over previous
//
#include <hip/hip_runtime.h>
#include <stdint.h>

// ---------- types / helpers ----------
typedef __bf16 bf16x8 __attribute__((ext_vector_type(8)));
typedef float  f32x4  __attribute__((ext_vector_type(4)));

#define DEV __device__ __forceinline__

DEV unsigned short f2bf(float f) {
    unsigned int u = __float_as_uint(f);
    unsigned int r = (u + 0x7fffu + ((u >> 16) & 1u)) >> 16;   // RNE
    return (unsigned short)r;
}
DEV float bf2f(unsigned short s) {
    return __uint_as_float(((unsigned int)s) << 16);
}

typedef __attribute__((address_space(1))) const void gv_t;
typedef __attribute__((address_space(3))) void lv_t;
DEV void stage16(const unsigned short* g, unsigned short* l) {
    // async global->LDS DMA, 16B/lane, LDS dest = wave-uniform base + lane*16
    __builtin_amdgcn_global_load_lds((gv_t*)g, (lv_t*)l, 16, 0, 0);
}

// ---------- vectorized fp32 -> bf16 (8 elements / thread) ----------
__global__ __launch_bounds__(256) void cvt8_kernel(const float* __restrict__ src,
                                                   unsigned short* __restrict__ dst, int n8) {
    int i = blockIdx.x * blockDim.x + threadIdx.x;
    if (i >= n8) return;
    const float4* s = (const float4*)(src + (size_t)i * 8);
    float4 x = s[0], y = s[1];
    uint4 pk; unsigned short* p = (unsigned short*)&pk;
    p[0]=f2bf(x.x); p[1]=f2bf(x.y); p[2]=f2bf(x.z); p[3]=f2bf(x.w);
    p[4]=f2bf(y.x); p[5]=f2bf(y.y); p[6]=f2bf(y.z); p[7]=f2bf(y.w);
    ((uint4*)dst)[i] = pk;
}

// ---------- q = joint_queries @ wq^T + bq  (coalesced wave-dot version) ----------
__global__ __launch_bounds__(256) void qproj2_kernel(const float* __restrict__ jq,
                                                     const float* __restrict__ ipw,
                                                     const float* __restrict__ ipb,
                                                     float* __restrict__ q) {
    __shared__ float zq[512];
    const int j = blockIdx.x, cq = blockIdx.y, t = threadIdx.x;
    zq[t] = jq[j * 512 + t];
    zq[t + 256] = jq[j * 512 + t + 256];
    __syncthreads();
    const int wv = t >> 6, lane = t & 63;
    for (int i = 0; i < 32; ++i) {
        int c = cq * 128 + wv * 32 + i;
        const float* wr = ipw + (size_t)c * 512 + lane * 8;
        float4 a = *(const float4*)wr;
        float4 bq = *(const float4*)(wr + 4);
        const float* zp = zq + lane * 8;
        float p = a.x*zp[0] + a.y*zp[1] + a.z*zp[2] + a.w*zp[3]
                + bq.x*zp[4] + bq.y*zp[5] + bq.z*zp[6] + bq.w*zp[7];
        for (int m = 32; m; m >>= 1) p += __shfl_xor(p, m);
        if (lane == 0) q[j * 512 + c] = p + ipb[c];
    }
}

// ---------- qk_fold[hj][e] = (1/8) sum_d q[j][h*64+d]*wk[h*64+d][e] -> Bcat rows 0..191 ----------
__global__ __launch_bounds__(256) void qkfold_kernel(const float* __restrict__ q,
                                                     const float* __restrict__ ipw,
                                                     const float* __restrict__ ipb,
                                                     unsigned short* __restrict__ Bcat,
                                                     float* __restrict__ bias1) {
    int hj = blockIdx.x;                // hj = h*24 + j
    int h = hj / 24, j = hj - h * 24;
    int t = threadIdx.x;
    __shared__ float qh[64];
    if (t < 64) qh[t] = q[j * 512 + h * 64 + t];
    __syncthreads();
    for (int e = t; e < 512; e += 256) {
        float acc = 0.f;
        for (int d = 0; d < 64; ++d)
            acc += qh[d] * ipw[(size_t)(512 + h * 64 + d) * 512 + e];
        Bcat[(size_t)hj * 512 + e] = f2bf(acc * 0.125f);
    }
    if (t == 0) {
        float acc = 0.f;
        for (int d = 0; d < 64; ++d) acc += qh[d] * ipb[512 + h * 64 + d];
        bias1[hj] = acc * 0.125f;
    }
}

// ---------- pad: Bcat rows 704..767 = 0, bias1[192..767] ----------
__global__ __launch_bounds__(256) void pad_kernel(unsigned short* __restrict__ Bcat,
                                                  float* __restrict__ bias1,
                                                  const float* __restrict__ ipb) {
    int idx = blockIdx.x * 256 + threadIdx.x;
    if (idx < 32768) Bcat[(size_t)704 * 512 + idx] = 0;
    if (idx < 512) bias1[192 + idx] = ipb[1024 + idx];
    if (idx < 64) bias1[704 + idx] = 0.f;
}

// ---------- opT[j][k] = bf16(opw[k][j]) ----------
__global__ __launch_bounds__(256) void transp_kernel(const float* __restrict__ opw,
                                                     unsigned short* __restrict__ opT) {
    int j = blockIdx.x;
    for (int k = threadIdx.x; k < 512; k += 256)
        opT[(size_t)j * 512 + k] = f2bf(opw[(size_t)k * 512 + j]);
}

// ---------- bfold[i] = w1[i,:].opb + b1[i]  (fp32) ----------
__global__ __launch_bounds__(256) void bfold_kernel(const float* __restrict__ w1,
                                                    const float* __restrict__ opb,
                                                    const float* __restrict__ b1,
                                                    float* __restrict__ bfold) {
    __shared__ float ob[512];
    int t = threadIdx.x;
    ob[t] = opb[t]; ob[t + 256] = opb[t + 256];
    __syncthreads();
    int i = blockIdx.x * 256 + t;
    float acc = b1[i];
    const float* wr = w1 + (size_t)i * 512;
    for (int k = 0; k < 512; ++k) acc += wr[k] * ob[k];
    bfold[i] = acc;
}

// ---------- gemm128: C(M,N)=A@B^T + bias, 128x128 tile, row-major C (for Wfold) ----------
__global__ __launch_bounds__(256) void gemm128(const unsigned short* __restrict__ A,
                                               const unsigned short* __restrict__ B,
                                               const float* __restrict__ bias,
                                               unsigned short* __restrict__ C,
                                               int K, int ldc) {
    __shared__ unsigned short As[4096];
    __shared__ unsigned short Bs[4096];
    const int tid = threadIdx.x, wv = tid >> 6, lane = tid & 63;
    const int m0 = blockIdx.y << 7, n0 = blockIdx.x << 7;
    const int wr = wv >> 1, wc = wv & 1;
    const int srow = lane >> 2, scol = (lane & 3) << 3;
    const int c0 = wv << 1;
    const unsigned short* pA = A + (size_t)(m0 + c0 * 16 + srow) * K + scol;
    const unsigned short* pB = B + (size_t)(n0 + c0 * 16 + srow) * K + scol;
    unsigned short* lA = As + (c0 << 9);
    unsigned short* lB = Bs + (c0 << 9);
    const size_t rowStep = (size_t)16 * K;

    f32x4 acc[4][4];
#pragma unroll
    for (int i = 0; i < 4; ++i)
#pragma unroll
        for (int j = 0; j < 4; ++j) acc[i][j] = f32x4{0.f, 0.f, 0.f, 0.f};

    const int row16 = lane & 15, kg8 = (lane >> 4) << 3;
    const int aoff = ((wr << 6) + row16) * 32 + kg8;
    const int boff = ((wc << 6) + row16) * 32 + kg8;

    for (int kb = 0; kb < K; kb += 32) {
        stage16(pA + kb, lA);
        stage16(pA + rowStep + kb, lA + 512);
        stage16(pB + kb, lB);
        stage16(pB + rowStep + kb, lB + 512);
        __syncthreads();
        bf16x8 a[4], b[4];
#pragma unroll
        for (int i = 0; i < 4; ++i) a[i] = *(const bf16x8*)&As[aoff + (i << 9)];
#pragma unroll
        for (int j = 0; j < 4; ++j) b[j] = *(const bf16x8*)&Bs[boff + (j << 9)];
#pragma unroll
        for (int i = 0; i < 4; ++i)
#pragma unroll
            for (int j = 0; j < 4; ++j)
                acc[i][j] = __builtin_amdgcn_mfma_f32_16x16x32_bf16(a[i], b[j], acc[i][j], 0, 0, 0);
        __syncthreads();
    }
    const int cg = lane >> 4, col = lane & 15;
#pragma unroll
    for (int j = 0; j < 4; ++j) {
        int gn = n0 + (wc << 6) + (j << 4) + col;
        float bv = bias ? bias[gn] : 0.f;
#pragma unroll
        for (int i = 0; i < 4; ++i) {
            int gmb = m0 + (wr << 6) + (i << 4) + (cg << 2);
#pragma unroll
            for (int rr = 0; rr < 4; ++rr)
                C[(size_t)(gmb + rr) * ldc + gn] = f2bf(acc[i][j][rr] + bv);
        }
    }
}

// ================================================================================
// gemm256T v2: software-pipelined fragments. 256x256 tile, BK=32, 8 waves,
// 4-deep LDS ring, ONE barrier + ONE vmcnt gate per K-tile.
//
// Per tile c (steady state), per wave:
//   gate vmcnt(4)        -> tile c+1 landed (outstanding: stages c+1,c+2 -> keep 4)
//   s_barrier            -> cross-wave visibility + ring-overwrite safety
//   stage(c+3)           -> 4 global_load_lds into buf (c-1)&3
//   issue ds_read A1(c)  (4)            [reads overlap H0 MFMAs]
//   lgkmcnt(4)           -> B(c),A0(c) (read last tile) landed
//   16 MFMA rows 0-3     (acc[0..3][*])
//   issue ds_read B(c+1), A0(c+1) (8)   [reads overlap H1 MFMAs]
//   lgkmcnt(8)           -> A1(c) landed
//   16 MFMA rows 4-7     (acc[4..7][*])
// B-frags are read ONCE per tile (held in regs both halves): 12 reads/tile vs 16.
// B parity: even tiles use Be, odd use Bo. sched_barrier(0) after every waitcnt
// (rule #18) also fences read groups so the lgkm counts are exact.
// Gate ledger: stages issued after barrier; at tile-c gate outstanding = c+1,c+2
// (8) -> vmcnt(4). Tail: c=13 gate 4, c=14 gate 0 (tile 15 landed), c=15 gate 0.
// ================================================================================
#define RD_B(DST, c_)                                                          \
  { const unsigned short* Bb_ = &lds[(c_) & 3][1][bhalf][bqoff];               \
    DST[0] = *(const bf16x8*)&Bb_[rdo];                                        \
    DST[1] = *(const bf16x8*)&Bb_[rdo + 512];                                  \
    DST[2] = *(const bf16x8*)&Bb_[rdo + 1024];                                 \
    DST[3] = *(const bf16x8*)&Bb_[rdo + 1536]; }

#define RD_A(DST, c_, base_)                                                   \
  { const unsigned short* Ab_ = &lds[(c_) & 3][0][wr][0];                      \
    DST[0] = *(const bf16x8*)&Ab_[rdo + ((base_) + 0) * 512];                  \
    DST[1] = *(const bf16x8*)&Ab_[rdo + ((base_) + 1) * 512];                  \
    DST[2] = *(const bf16x8*)&Ab_[rdo + ((base_) + 2) * 512];                  \
    DST[3] = *(const bf16x8*)&Ab_[rdo + ((base_) + 3) * 512]; }

#define MFMA16(b_, AR, BR)                                                                              \
    acc[(b_)+0][0] = __builtin_amdgcn_mfma_f32_16x16x32_bf16(AR[0], BR[0], acc[(b_)+0][0], 0, 0, 0);    \
    acc[(b_)+0][1] = __builtin_amdgcn_mfma_f32_16x16x32_bf16(AR[0], BR[1], acc[(b_)+0][1], 0, 0, 0);    \
    acc[(b_)+0][2] = __builtin_amdgcn_mfma_f32_16x16x32_bf16(AR[0], BR[2], acc[(b_)+0][2], 0, 0, 0);    \
    acc[(b_)+0][3] = __builtin_amdgcn_mfma_f32_16x16x32_bf16(AR[0], BR[3], acc[(b_)+0][3], 0, 0, 0);    \
    acc[(b_)+1][0] = __builtin_amdgcn_mfma_f32_16x16x32_bf16(AR[1], BR[0], acc[(b_)+1][0], 0, 0, 0);    \
    acc[(b_)+1][1] = __builtin_amdgcn_mfma_f32_16x16x32_bf16(AR[1], BR[1], acc[(b_)+1][1], 0, 0, 0);    \
    acc[(b_)+1][2] = __builtin_amdgcn_mfma_f32_16x16x32_bf16(AR[1], BR[2], acc[(b_)+1][2], 0, 0, 0);    \
    acc[(b_)+1][3] = __builtin_amdgcn_mfma_f32_16x16x32_bf16(AR[1], BR[3], acc[(b_)+1][3], 0, 0, 0);    \
    acc[(b_)+2][0] = __builtin_amdgcn_mfma_f32_16x16x32_bf16(AR[2], BR[0], acc[(b_)+2][0], 0, 0, 0);    \
    acc[(b_)+2][1] = __builtin_amdgcn_mfma_f32_16x16x32_bf16(AR[2], BR[1], acc[(b_)+2][1], 0, 0, 0);    \
    acc[(b_)+2][2] = __builtin_amdgcn_mfma_f32_16x16x32_bf16(AR[2], BR[2], acc[(b_)+2][2], 0, 0, 0);    \
    acc[(b_)+2][3] = __builtin_amdgcn_mfma_f32_16x16x32_bf16(AR[2], BR[3], acc[(b_)+2][3], 0, 0, 0);    \
    acc[(b_)+3][0] = __builtin_amdgcn_mfma_f32_16x16x32_bf16(AR[3], BR[0], acc[(b_)+3][0], 0, 0, 0);    \
    acc[(b_)+3][1] = __builtin_amdgcn_mfma_f32_16x16x32_bf16(AR[3], BR[1], acc[(b_)+3][1], 0, 0, 0);    \
    acc[(b_)+3][2] = __builtin_amdgcn_mfma_f32_16x16x32_bf16(AR[3], BR[2], acc[(b_)+3][2], 0, 0, 0);    \
    acc[(b_)+3][3] = __builtin_amdgcn_mfma_f32_16x16x32_bf16(AR[3], BR[3], acc[(b_)+3][3], 0, 0, 0);

#define G_TILE(c_, BC, BN, STAGE_, GATE_, RDN_, W2_)                           \
  asm volatile("s_waitcnt vmcnt(" GATE_ ")" ::: "memory");                     \
  __builtin_amdgcn_s_barrier();                                                \
  __builtin_amdgcn_sched_barrier(0);                                           \
  if (STAGE_) { const int tt_ = (c_) + 3;                                      \
    stage16(pA0 + tt_ * 32, &lds[tt_ & 3][0][0][w << 9]);                      \
    stage16(pA1 + tt_ * 32, &lds[tt_ & 3][0][1][w << 9]);                      \
    stage16(pB0 + tt_ * 32, &lds[tt_ & 3][1][0][w << 9]);                      \
    stage16(pB1 + tt_ * 32, &lds[tt_ & 3][1][1][w << 9]); }                    \
  RD_A(A1r, c_, 4)                                                             \
  asm volatile("s_waitcnt lgkmcnt(4)" ::: "memory");                           \
  __builtin_amdgcn_sched_barrier(0);                                           \
  __builtin_amdgcn_s_setprio(1);                                               \
  MFMA16(0, A0r, BC)                                                           \
  __builtin_amdgcn_s_setprio(0);                                               \
  if (RDN_) { RD_B(BN, (c_) + 1) RD_A(A0r, (c_) + 1, 0) }                      \
  asm volatile("s_waitcnt lgkmcnt(" W2_ ")" ::: "memory");                     \
  __builtin_amdgcn_sched_barrier(0);                                           \
  __builtin_amdgcn_s_setprio(1);                                               \
  MFMA16(4, A1r, BC)                                                           \
  __builtin_amdgcn_s_setprio(0);

__global__ __launch_bounds__(512, 2) void gemm256T(const unsigned short* __restrict__ A,
                                                   const unsigned short* __restrict__ B,
                                                   const float* __restrict__ bias,
                                                   unsigned short* __restrict__ CT) {
    constexpr int K = 512;
    constexpr int LDCT = 131072;
    constexpr int NSTORE = 704;
    // [buf 0..3][A=0/B=1][half 0..1][128 rows x 32 cols] = 128 KB
    __shared__ unsigned short lds[4][2][2][4096];

    const int tid = threadIdx.x;
    const int w = tid >> 6, l = tid & 63;
    const int wr = w >> 2, wc = w & 3;               // 2x4 wave grid -> 128x64 per wave
    const int row16 = l & 15, kchunk = l >> 4;       // fragment coords
    const int cg = l >> 4, col = l & 15;             // C/D layout coords

    // bijective XCD swizzle: 1536 wgs = 8 XCDs x 192; each XCD gets contiguous m-range
    const int bid = blockIdx.x;
    const int wg = (bid & 7) * 192 + (bid >> 3);
    const int mt = wg / 3, nt = wg - mt * 3;
    const int m0 = mt << 8, n0 = nt << 8;

    // staging source (per-thread), pre-swizzled chunk:  chunk' = chunk ^ ((row>>1)&3)
    const int st_r = (w << 4) + (l >> 2);            // row within 128-row half
    const int st_c = (l & 3) ^ ((l >> 3) & 3);       // logical 16B chunk for this lane
    const unsigned short* pA0 = A + (size_t)(m0 + st_r) * K + (st_c << 3);
    const unsigned short* pA1 = A + (size_t)(m0 + 128 + st_r) * K + (st_c << 3);
    const unsigned short* pB0 = B + (size_t)(n0 + st_r) * K + (st_c << 3);
    const unsigned short* pB1 = B + (size_t)(n0 + 128 + st_r) * K + (st_c << 3);

    // ds_read offset in shorts: row16*32 + swizzled_chunk*8 (same XOR as staging)
    const int rdo = row16 * 32 + ((kchunk ^ ((row16 >> 1) & 3)) << 3);
    const int bhalf = wc >> 1, bqoff = (wc & 1) << 11;   // B half + 64-row sub-offset

    f32x4 acc[8][4];
#pragma unroll
    for (int i = 0; i < 8; ++i)
#pragma unroll
        for (int j = 0; j < 4; ++j) acc[i][j] = f32x4{0.f, 0.f, 0.f, 0.f};

    bf16x8 Be[4], Bo[4], A0r[4], A1r[4];

    // prologue: stage tiles 0,1,2 (12 loads/wave); gate tiles 0,1 landed
#pragma unroll
    for (int t = 0; t < 3; ++t) {
        stage16(pA0 + t * 32, &lds[t][0][0][w << 9]);
        stage16(pA1 + t * 32, &lds[t][0][1][w << 9]);
        stage16(pB0 + t * 32, &lds[t][1][0][w << 9]);
        stage16(pB1 + t * 32, &lds[t][1][1][w << 9]);
    }
    asm volatile("s_waitcnt vmcnt(4)" ::: "memory");
    __builtin_amdgcn_s_barrier();
    __builtin_amdgcn_sched_barrier(0);
    // pre-read tile 0 fragments (B once, A rows 0-3)
    RD_B(Be, 0)
    RD_A(A0r, 0, 0)

    G_TILE(0,  Be, Bo, 1, "4", 1, "8")
    G_TILE(1,  Bo, Be, 1, "4", 1, "8")
    G_TILE(2,  Be, Bo, 1, "4", 1, "8")
    G_TILE(3,  Bo, Be, 1, "4", 1, "8")
    G_TILE(4,  Be, Bo, 1, "4", 1, "8")
    G_TILE(5,  Bo, Be, 1, "4", 1, "8")
    G_TILE(6,  Be, Bo, 1, "4", 1, "8")
    G_TILE(7,  Bo, Be, 1, "4", 1, "8")
    G_TILE(8,  Be, Bo, 1, "4", 1, "8")
    G_TILE(9,  Bo, Be, 1, "4", 1, "8")
    G_TILE(10, Be, Bo, 1, "4", 1, "8")
    G_TILE(11, Bo, Be, 1, "4", 1, "8")
    G_TILE(12, Be, Bo, 1, "4", 1, "8")
    G_TILE(13, Bo, Be, 0, "4", 1, "8")
    G_TILE(14, Be, Bo, 0, "0", 1, "8")
    G_TILE(15, Bo, Be, 0, "0", 0, "0")

    // epilogue: transposed bf16 store, 8B packed per 4 rows
#pragma unroll
    for (int nf = 0; nf < 4; ++nf) {
        int gn = n0 + (wc << 6) + (nf << 4) + col;
        if (gn < NSTORE) {
            float bv = bias[gn];
            unsigned short* rowp = CT + (size_t)gn * LDCT;
#pragma unroll
            for (int mf = 0; mf < 8; ++mf) {
                int gmb = m0 + (wr << 7) + (mf << 4) + (cg << 2);
                ushort4 pk;
                pk.x = f2bf(acc[mf][nf][0] + bv);
                pk.y = f2bf(acc[mf][nf][1] + bv);
                pk.z = f2bf(acc[mf][nf][2] + bv);
                pk.w = f2bf(acc[mf][nf][3] + bv);
                *(ushort4*)(rowp + gmb) = pk;
            }
        }
    }
}

// ---------- mega: per-b attention (softmax+PV) + Wfold GEMM + LN/SiLU/w2 + chain ----------
__global__ __launch_bounds__(256) void mega_kernel(const unsigned short* __restrict__ scTV,
                                                   const unsigned short* __restrict__ Wfold,
                                                   const float* __restrict__ bfold,
                                                   const float* __restrict__ ln_g,
                                                   const float* __restrict__ ln_b,
                                                   const float* __restrict__ w2,
                                                   const float* __restrict__ b2,
                                                   const int* __restrict__ parent,
                                                   float* __restrict__ out) {
    const int b = blockIdx.x, tid = threadIdx.x;
    const int wv = tid >> 6, lane = tid & 63;
    const int row16 = lane & 15, kg8 = (lane >> 4) << 3;
    const int cg = lane >> 4, col = lane & 15;

    __shared__ unsigned short pmat[32 * 128];    // P (one head), rows 24..31 garbage (unused)
    __shared__ unsigned short vtB[16384];        // phase A: vt[64][128]; phase B: Bst[4][128*32]
    __shared__ unsigned short otile[32 * 520];   // o-tile, stride 520 (16B-aligned, 2-way banks)
    __shared__ float red1[32][4], red2[32][4];
    __shared__ float mus[32], rstds[32];
    __shared__ float dred[24][4][4];
    __shared__ float offs[24][3];

    const size_t colbase = (size_t)b * 128 + (size_t)(lane & 15) * 8;

    // ================= Phase A: attention =================
    for (int h = 0; h < 8; ++h) {
        if (wv < 3) {   // stage P rows: waves 0..2, 8 rows each (2 DMA instrs)
            const size_t r0 = (size_t)(h * 24 + 8 * wv + (lane >> 4));
            stage16(scTV + r0 * 131072 + colbase, pmat + (8 * wv) * 128);
            stage16(scTV + (r0 + 4) * 131072 + colbase, pmat + (8 * wv + 4) * 128);
        }
#pragma unroll
        for (int g = 0; g < 4; ++g) {   // stage V^T rows: each wave 16 rows
            const size_t r0 = (size_t)(192 + h * 64 + 16 * wv + 4 * g + (lane >> 4));
            stage16(scTV + r0 * 131072 + colbase, vtB + (16 * wv + 4 * g) * 128);
        }
        __syncthreads();

        // softmax over s (128) for rows wv*6 .. +6
        for (int i = 0; i < 6; ++i) {
            int j = wv * 6 + i;
            float x0 = bf2f(pmat[j * 128 + lane]);
            float x1 = bf2f(pmat[j * 128 + 64 + lane]);
            float mx = fmaxf(x0, x1);
            for (int m = 32; m; m >>= 1) mx = fmaxf(mx, __shfl_xor(mx, m));
            float e0 = __expf(x0 - mx), e1 = __expf(x1 - mx);
            float sm = e0 + e1;
            for (int m = 32; m; m >>= 1) sm += __shfl_xor(sm, m);
            float inv = 1.f / sm;
            pmat[j * 128 + lane] = f2bf(e0 * inv);
            pmat[j * 128 + 64 + lane] = f2bf(e1 * inv);
        }
        __syncthreads();

        // PV: wave handles d-cols [wv*16, wv*16+16)
        f32x4 pv0 = {0.f,0.f,0.f,0.f}, pv1 = {0.f,0.f,0.f,0.f};
#pragma unroll
        for (int ks = 0; ks < 4; ++ks) {
            bf16x8 a0 = *(const bf16x8*)&pmat[row16 * 128 + ks * 32 + kg8];
            bf16x8 a1 = *(const bf16x8*)&pmat[(16 + row16) * 128 + ks * 32 + kg8];
            bf16x8 bf = *(const bf16x8*)&vtB[(wv * 16 + row16) * 128 + ks * 32 + kg8];
            pv0 = __builtin_amdgcn_mfma_f32_16x16x32_bf16(a0, bf, pv0, 0, 0, 0);
            pv1 = __builtin_amdgcn_mfma_f32_16x16x32_bf16(a1, bf, pv1, 0, 0, 0);
        }
#pragma unroll
        for (int rr = 0; rr < 4; ++rr) {
            int j0 = cg * 4 + rr;
            otile[j0 * 520 + h * 64 + wv * 16 + col] = f2bf(pv0[rr]);
            int j1 = 16 + cg * 4 + rr;
            if (j1 < 24)
                otile[j1 * 520 + h * 64 + wv * 16 + col] = f2bf(pv1[rr]);
        }
        __syncthreads();
    }

    // ================= Phase B: h = otile @ Wfold^T + bfold =================
    const int ns = wv << 7;                      // wave's 128-col slice
    unsigned short* Bst = vtB + (wv << 12);      // 8 KB per wave

    f32x4 acc[2][8];
#pragma unroll
    for (int mt = 0; mt < 2; ++mt)
#pragma unroll
        for (int nt = 0; nt < 8; ++nt) acc[mt][nt] = f32x4{0.f,0.f,0.f,0.f};

    for (int kb = 0; kb < 512; kb += 32) {
#pragma unroll
        for (int g = 0; g < 8; ++g)
            stage16(Wfold + (size_t)(ns + 16 * g + (lane >> 2)) * 512 + kb + (lane & 3) * 8,
                    Bst + 16 * g * 32);
        __syncthreads();
        bf16x8 a0 = *(const bf16x8*)&otile[row16 * 520 + kb + kg8];
        bf16x8 a1 = *(const bf16x8*)&otile[(16 + row16) * 520 + kb + kg8];
#pragma unroll
        for (int nt = 0; nt < 8; ++nt) {
            bf16x8 bf = *(const bf16x8*)&Bst[(nt * 16 + row16) * 32 + kg8];
            acc[0][nt] = __builtin_amdgcn_mfma_f32_16x16x32_bf16(a0, bf, acc[0][nt], 0, 0, 0);
            acc[1][nt] = __builtin_amdgcn_mfma_f32_16x16x32_bf16(a1, bf, acc[1][nt], 0, 0, 0);
        }
        __syncthreads();
    }

    // bias + LN stats (per-row partial sums, 16-lane groups then cross-wave via LDS)
    int gcol[8]; float bvv[8];
#pragma unroll
    for (int nt = 0; nt < 8; ++nt) { gcol[nt] = ns + nt * 16 + col; bvv[nt] = bfold[gcol[nt]]; }
#pragma unroll
    for (int mt = 0; mt < 2; ++mt)
#pragma unroll
        for (int nt = 0; nt < 8; ++nt)
#pragma unroll
            for (int rr = 0; rr < 4; ++rr) acc[mt][nt][rr] += bvv[nt];

#pragma unroll
    for (int mt = 0; mt < 2; ++mt)
#pragma unroll
        for (int rr = 0; rr < 4; ++rr) {
            float s1 = 0.f, s2 = 0.f;
#pragma unroll
            for (int nt = 0; nt < 8; ++nt) { float v = acc[mt][nt][rr]; s1 += v; s2 += v * v; }
            s1 += __shfl_xor(s1, 1); s2 += __shfl_xor(s2, 1);
            s1 += __shfl_xor(s1, 2); s2 += __shfl_xor(s2, 2);
            s1 += __shfl_xor(s1, 4); s2 += __shfl_xor(s2, 4);
            s1 += __shfl_xor(s1, 8); s2 += __shfl_xor(s2, 8);
            if (col == 0) { int r = mt * 16 + cg * 4 + rr; red1[r][wv] = s1; red2[r][wv] = s2; }
        }
    __syncthreads();
    if (tid < 32) {
        float s1 = red1[tid][0] + red1[tid][1] + red1[tid][2] + red1[tid][3];
        float s2 = red2[tid][0] + red2[tid][1] + red2[tid][2] + red2[tid][3];
        float mu = s1 * (1.f / 512.f);
        float var = s2 * (1.f / 512.f) - mu * mu;
        mus[tid] = mu; rstds[tid] = rsqrtf(var + 1e-5f);
    }
    __syncthreads();

    // LN + SiLU + w2 partial dots
    float gg[8], bb[8], w2v[4][8];
#pragma unroll
    for (int nt = 0; nt < 8; ++nt) { gg[nt] = ln_g[gcol[nt]]; bb[nt] = ln_b[gcol[nt]]; }
#pragma unroll
    for (int c = 0; c < 4; ++c)
#pragma unroll
        for (int nt = 0; nt < 8; ++nt) w2v[c][nt] = w2[c * 512 + gcol[nt]];

#pragma unroll
    for (int mt = 0; mt < 2; ++mt)
#pragma unroll
        for (int rr = 0; rr < 4; ++rr) {
            int r = mt * 16 + cg * 4 + rr;
            float mu = mus[r], rs = rstds[r];
            float d0 = 0.f, d1 = 0.f, d2 = 0.f, d3 = 0.f;
#pragma unroll
            for (int nt = 0; nt < 8; ++nt) {
                float y = (acc[mt][nt][rr] - mu) * rs * gg[nt] + bb[nt];
                float sv = y / (1.f + __expf(-y));
                d0 += sv * w2v[0][nt]; d1 += sv * w2v[1][nt];
                d2 += sv * w2v[2][nt]; d3 += sv * w2v[3][nt];
            }
            d0 += __shfl_xor(d0, 1); d1 += __shfl_xor(d1, 1); d2 += __shfl_xor(d2, 1); d3 += __shfl_xor(d3, 1);
            d0 += __shfl_xor(d0, 2); d1 += __shfl_xor(d1, 2); d2 += __shfl_xor(d2, 2); d3 += __shfl_xor(d3, 2);
            d0 += __shfl_xor(d0, 4); d1 += __shfl_xor(d1, 4); d2 += __shfl_xor(d2, 4); d3 += __shfl_xor(d3, 4);
            d0 += __shfl_xor(d0, 8); d1 += __shfl_xor(d1, 8); d2 += __shfl_xor(d2, 8); d3 += __shfl_xor(d3, 8);
            if (col == 0 && r < 24) {
                dred[r][wv][0] = d0; dred[r][wv][1] = d1;
                dred[r][wv][2] = d2; dred[r][wv][3] = d3;
            }
        }
    __syncthreads();

    float* out_joints = out;
    float* out_off    = out + 73728;
    float* out_len    = out + 147456;
    if (tid < 24) {
        int j = tid;
        float rv[4];
#pragma unroll
        for (int c = 0; c < 4; ++c)
            rv[c] = dred[j][0][c] + dred[j][1][c] + dred[j][2][c] + dred[j][3][c] + b2[c];
        size_t ob = ((size_t)b * 24 + j) * 3;
        if (j == 0) {
            offs[0][0] = offs[0][1] = offs[0][2] = 0.f;
            out_off[ob] = 0.f; out_off[ob + 1] = 0.f; out_off[ob + 2] = 0.f;
        } else {
            float nrm = sqrtf(rv[0]*rv[0] + rv[1]*rv[1] + rv[2]*rv[2]);
            float inv = 1.f / fmaxf(nrm, 1e-6f);
            float lr = rv[3];
            float L = (lr > 0.f) ? lr + log1pf(expf(-lr)) : log1pf(expf(lr));
            float o0 = rv[0]*inv*L, o1 = rv[1]*inv*L, o2 = rv[2]*inv*L;
            offs[j][0] = o0; offs[j][1] = o1; offs[j][2] = o2;
            out_off[ob] = o0; out_off[ob + 1] = o1; out_off[ob + 2] = o2;
            out_len[(size_t)b * 23 + j - 1] = L;
        }
    }
    __syncthreads();
    if (tid < 3) {
        int d = tid;
        float cum[24]; cum[0] = 0.f;
        out_joints[(size_t)b * 24 * 3 + d] = 0.f;
        for (int j = 1; j < 24; ++j) {
            cum[j] = offs[j][d] + cum[parent[j]];
            out_joints[((size_t)b * 24 + j) * 3 + d] = cum[j];
        }
    }
}

// ---------- launch ----------
extern "C" void kernel_launch(void* const* d_in, const int* in_sizes, int n_in,
                              void* d_out, int out_size, void* d_ws, size_t ws_size,
                              hipStream_t stream) {
    const float* z    = (const float*)d_in[0];   // (1024,128,512)
    const float* jq   = (const float*)d_in[1];   // (1,24,512)
    const float* ipw  = (const float*)d_in[2];   // (1536,512)
    const float* ipb  = (const float*)d_in[3];   // (1536,)
    const float* opw  = (const float*)d_in[4];   // (512,512)
    const float* opb  = (const float*)d_in[5];
    const float* w1   = (const float*)d_in[6];   // (512,512)
    const float* b1   = (const float*)d_in[7];
    const float* lng  = (const float*)d_in[8];
    const float* lnb  = (const float*)d_in[9];
    const float* w2   = (const float*)d_in[10];  // (4,512)
    const float* b2   = (const float*)d_in[11];
    const int* parent = (const int*)d_in[12];
    float* out = (float*)d_out;

    char* ws = (char*)d_ws;
    size_t off = 0;
    auto alloc = [&](size_t bytes) {
        off = (off + 255) & ~(size_t)255;
        char* p = ws + off;
        off += bytes;
        return p;
    };

    unsigned short* zb    = (unsigned short*)alloc((size_t)67108864 * 2);        // 134 MB
    unsigned short* scTV  = (unsigned short*)alloc((size_t)704 * 131072 * 2);    // 184.5 MB
    unsigned short* Bcat  = (unsigned short*)alloc((size_t)768 * 512 * 2);
    float*          bias1 = (float*)alloc(768 * 4);
    float*          qf    = (float*)alloc((size_t)24 * 512 * 4);
    unsigned short* opT   = (unsigned short*)alloc((size_t)512 * 512 * 2);
    unsigned short* w1b   = (unsigned short*)alloc((size_t)512 * 512 * 2);
    unsigned short* Wfold = (unsigned short*)alloc((size_t)512 * 512 * 2);
    float*          bfold = (float*)alloc(512 * 4);

    // --- prep ---
    cvt8_kernel<<<32768, 256, 0, stream>>>(z, zb, 8388608);                       // z -> bf16
    cvt8_kernel<<<128, 256, 0, stream>>>(ipw + (size_t)1024 * 512,
                                         Bcat + (size_t)192 * 512, 32768);        // wv rows 192..703
    cvt8_kernel<<<128, 256, 0, stream>>>(w1, w1b, 32768);
    qproj2_kernel<<<dim3(24, 4), 256, 0, stream>>>(jq, ipw, ipb, qf);
    qkfold_kernel<<<192, 256, 0, stream>>>(qf, ipw, ipb, Bcat, bias1);            // rows 0..191
    pad_kernel<<<128, 256, 0, stream>>>(Bcat, bias1, ipb);
    transp_kernel<<<512, 256, 0, stream>>>(opw, opT);
    bfold_kernel<<<2, 256, 0, stream>>>(w1, opb, b1, bfold);
    gemm128<<<dim3(4, 4), 256, 0, stream>>>(w1b, opT, nullptr, Wfold, 512, 512);  // Wfold = w1@opw

    // --- fused scores|V GEMM, 256^2 tile, software-pipelined, transposed store ---
    gemm256T<<<1536, 512, 0, stream>>>(zb, Bcat, bias1, scTV);

    // --- per-b mega: attention + Wfold GEMM + LN/SiLU/w2 + chain ---
    mega_kernel<<<1024, 256, 0, stream>>>(scTV, Wfold, bfold, lng, lnb, w2, b2, parent, out);
}